// Round 9
// baseline (139.549 us; speedup 1.0000x reference)
//
#include <hip/hip_runtime.h>
#include <hip/hip_bf16.h>

typedef unsigned short u16;
typedef __attribute__((ext_vector_type(8))) short short8;
typedef __attribute__((ext_vector_type(2))) float f32x2;
typedef __attribute__((ext_vector_type(4))) float f32x4;
typedef __attribute__((ext_vector_type(16))) float f32x16;

#define N_NODES 4096
#define FIN 512
#define KH 8
#define FO 128
#define DM 1024   // KH*FO
#define LOG2E 1.44269504088896340736f

__device__ __forceinline__ void gload16(const u16* g, u16* l) {
    __builtin_amdgcn_global_load_lds(
        (const __attribute__((address_space(1))) unsigned int*)g,
        (__attribute__((address_space(3))) unsigned int*)l,
        16, 0, 0);
}

__device__ __forceinline__ unsigned pk_bf16(float lo, float hi) {
    unsigned r;
    asm("v_cvt_pk_bf16_f32 %0, %1, %2" : "=v"(r) : "v"(lo), "v"(hi));
    return r;
}

// (c*d, c'*d') in one packed-fp32 mul, then max of the two branches.
__device__ __forceinline__ float pkmul_max(f32x2 a, f32x2 b) {
    f32x2 r;
    asm("v_pk_mul_f32 %0, %1, %2" : "=v"(r) : "v"(a), "v"(b));
    return fmaxf(r.x, r.y);
}

// ---------------- Kernel P: split fp32 -> (hi, lo) bf16 ----------------
__global__ __launch_bounds__(256) void split_bf16(const float* __restrict__ src,
                                                  u16* __restrict__ hi,
                                                  u16* __restrict__ lo,
                                                  int n4) {
    int idx = blockIdx.x * 256 + threadIdx.x;
    if (idx >= n4) return;
    float4 v = ((const float4*)src)[idx];
    unsigned h01 = pk_bf16(v.x, v.y);
    unsigned h23 = pk_bf16(v.z, v.w);
    float hx = __uint_as_float(h01 << 16);
    float hy = __uint_as_float(h01 & 0xffff0000u);
    float hz = __uint_as_float(h23 << 16);
    float hw = __uint_as_float(h23 & 0xffff0000u);
    unsigned l01 = pk_bf16(v.x - hx, v.y - hy);
    unsigned l23 = pk_bf16(v.z - hz, v.w - hw);
    uint2 hv; hv.x = h01; hv.y = h23;
    uint2 lv; lv.x = l01; lv.y = l23;
    ((uint2*)hi)[idx] = hv;
    ((uint2*)lo)[idx] = lv;
}

// ---------------- Kernel A: MFMA split-bf16 GEMM + bias + C/D factor tables + transpose ----
__global__ __launch_bounds__(512) void gemm_mfma(const u16* __restrict__ Xh,
                                                 const u16* __restrict__ Xl,
                                                 const u16* __restrict__ Wh,
                                                 const u16* __restrict__ Wl,
                                                 const float* __restrict__ bias,
                                                 const float* __restrict__ aL,
                                                 const float* __restrict__ aR,
                                                 float2* __restrict__ C2,
                                                 float2* __restrict__ D2,
                                                 u16* __restrict__ HbT) {
    const int khead = blockIdx.x;
    const int n0 = blockIdx.y * 128;
    const int tid = threadIdx.x;
    const int w = tid >> 6, lane = tid & 63;
    const int wr = w >> 1, wc = w & 1;
    const int c = lane & 31, half = lane >> 5;

    __shared__ u16 S[2][16384];

    const int sa = w >> 1;
    const int shv = w & 1;
    const int scl = lane & 3;
    const int ssw = ((lane >> 2) ^ (lane >> 4)) & 3;
    const int sgc = scl ^ ssw;
    const u16* gb; int growbase;
    if (sa == 0)      { gb = Xh; growbase = n0; }
    else if (sa == 1) { gb = Xl; growbase = n0; }
    else if (sa == 2) { gb = Wh; growbase = khead * 128; }
    else              { gb = Wl; growbase = khead * 128; }
    const u16* glb = gb + (size_t)(growbase + shv * 64 + (lane >> 2)) * FIN + sgc * 8;
    const int sldsoff = sa * 4096 + shv * 64 * 32;

    const int sw = ((c) ^ (c >> 2)) & 3;
    const int aoff = (wr * 32 + c) * 32;
    const int boff0 = 8192 + (wc * 64 + c) * 32;
    const int boff1 = 8192 + (wc * 64 + 32 + c) * 32;

    f32x16 acc0, acc1;
#pragma unroll
    for (int i = 0; i < 16; ++i) { acc0[i] = 0.f; acc1[i] = 0.f; }

#pragma unroll
    for (int i = 0; i < 4; ++i)
        gload16(glb + (size_t)i * 16 * FIN, &S[0][sldsoff + i * 512]);
    __syncthreads();

    int cur = 0;
    for (int kt = 0; kt < 16; ++kt) {
        if (kt < 15) {
            const u16* gsrc = glb + (kt + 1) * 32;
            u16* dst = &S[cur ^ 1][sldsoff];
#pragma unroll
            for (int i = 0; i < 4; ++i)
                gload16(gsrc + (size_t)i * 16 * FIN, dst + i * 512);
        }

        const u16* sp = S[cur];
        short8 ah[2], al8[2], bh[2][2], bl8[2][2];
#pragma unroll
        for (int ks = 0; ks < 2; ++ks) {
            int ch = ((ks * 2 + half) ^ sw) * 8;
            ah[ks]     = *(const short8*)&sp[aoff + ch];
            al8[ks]    = *(const short8*)&sp[4096 + aoff + ch];
            bh[0][ks]  = *(const short8*)&sp[boff0 + ch];
            bl8[0][ks] = *(const short8*)&sp[boff0 + 4096 + ch];
            bh[1][ks]  = *(const short8*)&sp[boff1 + ch];
            bl8[1][ks] = *(const short8*)&sp[boff1 + 4096 + ch];
        }
#pragma unroll
        for (int ks = 0; ks < 2; ++ks) {
            acc0 = __builtin_amdgcn_mfma_f32_32x32x16_bf16(ah[ks], bh[0][ks], acc0, 0, 0, 0);
            acc0 = __builtin_amdgcn_mfma_f32_32x32x16_bf16(ah[ks], bl8[0][ks], acc0, 0, 0, 0);
            acc0 = __builtin_amdgcn_mfma_f32_32x32x16_bf16(al8[ks], bh[0][ks], acc0, 0, 0, 0);
            acc1 = __builtin_amdgcn_mfma_f32_32x32x16_bf16(ah[ks], bh[1][ks], acc1, 0, 0, 0);
            acc1 = __builtin_amdgcn_mfma_f32_32x32x16_bf16(ah[ks], bl8[1][ks], acc1, 0, 0, 0);
            acc1 = __builtin_amdgcn_mfma_f32_32x32x16_bf16(al8[ks], bh[1][ks], acc1, 0, 0, 0);
        }
        __syncthreads();
        cur ^= 1;
    }

    const int fglob = khead * FO + wc * 64 + c;
    float b0 = bias[fglob], b1 = bias[fglob + 32];
#pragma unroll
    for (int r = 0; r < 16; ++r) { acc0[r] += b0; acc1[r] += b1; }

    float alv0 = aL[fglob], alv1 = aL[fglob + 32];
    float arv0 = aR[fglob], arv1 = aR[fglob + 32];
    float pl[16], pr[16];
#pragma unroll
    for (int r = 0; r < 16; ++r) {
        pl[r] = acc0[r] * alv0 + acc1[r] * alv1;
        pr[r] = acc0[r] * arv0 + acc1[r] * arv1;
    }
#pragma unroll
    for (int off = 1; off < 32; off <<= 1) {
#pragma unroll
        for (int r = 0; r < 16; ++r) {
            pl[r] += __shfl_xor(pl[r], off);
            pr[r] += __shfl_xor(pr[r], off);
        }
    }

    u16* T = &S[0][0];
    float* LRf = (float*)&S[0][0] + 9216;

    if (c == 0) {
#pragma unroll
        for (int r = 0; r < 16; ++r) {
            int node = wr * 32 + (r & 3) + 8 * (r >> 2) + 4 * half;
            LRf[(wc * 2 + 0) * 128 + node] = pl[r];
            LRf[(wc * 2 + 1) * 128 + node] = pr[r];
        }
    }

#pragma unroll
    for (int q = 0; q < 4; ++q) {
        int nb = wr * 32 + q * 8 + 4 * half;
        unsigned p00 = pk_bf16(acc0[q * 4 + 0], acc0[q * 4 + 1]);
        unsigned p01 = pk_bf16(acc0[q * 4 + 2], acc0[q * 4 + 3]);
        unsigned p10 = pk_bf16(acc1[q * 4 + 0], acc1[q * 4 + 1]);
        unsigned p11 = pk_bf16(acc1[q * 4 + 2], acc1[q * 4 + 3]);
        *(unsigned*)&T[(wc * 64 + c) * 136 + nb]      = p00;
        *(unsigned*)&T[(wc * 64 + c) * 136 + nb + 2]  = p01;
        *(unsigned*)&T[(wc * 64 + 32 + c) * 136 + nb]     = p10;
        *(unsigned*)&T[(wc * 64 + 32 + c) * 136 + nb + 2] = p11;
    }
    __syncthreads();

    if (wc == 0) {
        int node = wr * 32 + (lane & 31);
        if (lane < 32) {
            float L = (LRf[0 * 128 + node] + LRf[2 * 128 + node]) * LOG2E;
            float2 cv; cv.x = exp2f(L); cv.y = exp2f(0.2f * L);
            C2[(size_t)khead * N_NODES + n0 + node] = cv;
        } else {
            float R = (LRf[1 * 128 + node] + LRf[3 * 128 + node]) * LOG2E;
            float2 dvv; dvv.x = exp2f(R); dvv.y = exp2f(0.2f * R);
            D2[(size_t)khead * N_NODES + n0 + node] = dvv;
        }
    }

    {
        int f = tid >> 2, q = tid & 3;
        const uint4* src = (const uint4*)&T[f * 136 + q * 32];
        uint4* dst = (uint4*)(HbT + (size_t)(khead * FO + f) * N_NODES + n0 + q * 32);
#pragma unroll
        for (int u = 0; u < 4; ++u) dst[u] = src[u];
    }
}

// ---------------- Kernel D: pack mask (int32 0/1) into bitmask ----------------
__global__ __launch_bounds__(256) void pack_mask(const int* __restrict__ mask,
                                                 unsigned long long* __restrict__ mb) {
    int gid = blockIdx.x * 256 + threadIdx.x;
    int wid = gid >> 6, lane = gid & 63;
    int v = mask[(size_t)wid * 64 + lane];
    unsigned long long bits = __ballot(v != 0);
    if (lane == 0) mb[wid] = bits;
}

// ---------------- Kernel C: flash-style masked softmax + PV aggregation ----------------
// Flat grid 512, head = blk&7 (head<->XCD pin). 512 thr = 8 waves:
// ns = w&1 (32-row n-slice), g = w>>1 (4-way m-split, 1024 m each, 32-m tiles).
// Per wave-iter: 8 ds_read_b128 (B amortized over 32 output rows — half of R8's LDS
// traffic). S accumulated on VALU (no ones-column MFMA) to fit 128-VGPR budget.
// Pipeline: D(t) loads -> stage(t+1) -> compute (P-gen auto-wait vmcnt(4), stage in
// flight through compute) -> lgkm0 + vmcnt(0)-on-aged + barrier (own-wait-then-barrier).
__global__ __launch_bounds__(512, 4) void gat_attn(const u16* __restrict__ HbT,
                                                   const float2* __restrict__ C2,
                                                   const float2* __restrict__ D2,
                                                   const unsigned* __restrict__ M32,
                                                   float* __restrict__ out) {
    const int blk = blockIdx.x;
    const int k = blk & 7;
    const int n0 = (blk >> 3) * 64;
    const int tid = threadIdx.x;
    const int w = tid >> 6, lane = tid & 63;
    const int ns = w & 1, g = w >> 1;
    const int fr = lane & 15, kg = lane >> 4;

    __shared__ u16 Ht[4][2][4096];   // [group][buf][128f x 32m swizzled] = 64 KB

    const int na0 = n0 + ns * 32 + fr;
    const int na1 = na0 + 16;
    float2 c0f = C2[(size_t)k * N_NODES + na0];
    float2 c1f = C2[(size_t)k * N_NODES + na1];
    f32x2 cc0; cc0.x = c0f.x; cc0.y = c0f.y;
    f32x2 cc1; cc1.x = c1f.x; cc1.y = c1f.y;
    const unsigned* mrow0 = M32 + (size_t)na0 * 128 + g * 32;
    const unsigned* mrow1 = M32 + (size_t)na1 * 128 + g * 32;

    f32x4 acc[2][8];
#pragma unroll
    for (int s = 0; s < 2; ++s)
#pragma unroll
        for (int c = 0; c < 8; ++c) acc[s][c] = 0.f;
    float S0 = 0.f, S1 = 0.f;

    // staging: wave (ns,g) stages rows ns*64..+63 of its group's 128f x 32m tile.
    // LDS linear: row f (stride 32 u16), chunk c_lds holds global chunk c_lds^sw(f),
    // sw(f) = (f>>1)&3. Lane l: row = l>>2 (+j*16), c_lds = l&3 -> gchunk = (l&3)^((l>>3)&3).
    const int srow = lane >> 2;
    const int gch = (lane & 3) ^ ((lane >> 3) & 3);
    const u16* gsb = HbT + (size_t)(k * FO + ns * 64 + srow) * N_NODES + g * 1024 + gch * 8;
    u16* ldsw = &Ht[g][0][ns * 2048];   // + buf*4096 + j*512 (HW adds lane*16B)

    // read: B-frag row c*16+fr, chunk kg^((fr>>1)&3)  (2-way max -> free)
    const int offb = fr * 32 + ((kg ^ ((fr >> 1) & 3)) << 3);
    const float2* Dk = D2 + (size_t)k * N_NODES + g * 1024 + kg * 8;

    // prologue: stage tile0 -> buf0; own-wait; barrier (partner's stage visible)
#pragma unroll
    for (int j = 0; j < 4; ++j)
        gload16(gsb + (size_t)j * 16 * N_NODES, ldsw + j * 512);
    asm volatile("s_waitcnt vmcnt(0)" ::: "memory");
    __builtin_amdgcn_s_barrier();

    for (int mt = 0; mt < 32; ++mt) {
        const int cur = mt & 1;
        // (1) D(t) + masks (6 loads, FIFO-first)
        const float4* dp = (const float4*)(Dk + mt * 32);
        float4 dq0 = dp[0], dq1 = dp[1], dq2 = dp[2], dq3 = dp[3];
        unsigned mw0 = mrow0[mt], mw1 = mrow1[mt];
        // (2) stage(t+1) -> other buf (aged a full compute phase before tail wait)
        {
            const u16* gs = gsb + (((mt + 1) & 31) << 5);
            u16* ld = ldsw + ((cur ^ 1) << 12);
#pragma unroll
            for (int j = 0; j < 4; ++j)
                gload16(gs + (size_t)j * 16 * N_NODES, ld + j * 512);
        }
        __builtin_amdgcn_sched_barrier(0);

        // (3) P-gen (compiler's D-wait = vmcnt(4): stage stays in flight)
        float dv[16] = {dq0.x, dq0.y, dq0.z, dq0.w, dq1.x, dq1.y, dq1.z, dq1.w,
                        dq2.x, dq2.y, dq2.z, dq2.w, dq3.x, dq3.y, dq3.z, dq3.w};
        unsigned mq0 = mw0 >> (kg * 8);
        unsigned mq1 = mw1 >> (kg * 8);
        float p0[8], p1[8];
#pragma unroll
        for (int v = 0; v < 8; ++v) {
            f32x2 dd; dd.x = dv[2 * v]; dd.y = dv[2 * v + 1];
            float pa = pkmul_max(cc0, dd);
            float pb = pkmul_max(cc1, dd);
            unsigned s0 = (unsigned)(((int)(mq0 << (31 - v))) >> 31);
            unsigned s1 = (unsigned)(((int)(mq1 << (31 - v))) >> 31);
            p0[v] = __uint_as_float(__float_as_uint(pa) & s0);
            p1[v] = __uint_as_float(__float_as_uint(pb) & s1);
        }
        union { unsigned u[4]; short8 s; } ua, ub;
#pragma unroll
        for (int vp = 0; vp < 4; ++vp) {
            ua.u[vp] = pk_bf16(p0[2 * vp], p0[2 * vp + 1]);
            ub.u[vp] = pk_bf16(p1[2 * vp], p1[2 * vp + 1]);
        }
        short8 a0 = ua.s, a1 = ub.s;
#pragma unroll
        for (int v = 0; v < 8; ++v) { S0 += p0[v]; S1 += p1[v]; }

        // (4) ds_read + MFMA (8 reads, 16 MFMAs)
        const u16* hb = &Ht[g][cur][0];
#pragma unroll
        for (int c = 0; c < 8; ++c) {
            short8 b = *(const short8*)(hb + c * 512 + offb);
            acc[0][c] = __builtin_amdgcn_mfma_f32_16x16x32_bf16(a0, b, acc[0][c], 0, 0, 0);
            acc[1][c] = __builtin_amdgcn_mfma_f32_16x16x32_bf16(a1, b, acc[1][c], 0, 0, 0);
        }
        // (5) own-wait-then-barrier (stage(t+1) aged; D already retired)
        asm volatile("s_waitcnt lgkmcnt(0)" ::: "memory");
        asm volatile("s_waitcnt vmcnt(0)" ::: "memory");
        __builtin_amdgcn_s_barrier();
    }

    __syncthreads();   // wrap-stage landed (vmcnt(0) above); safe to reuse LDS

    // ---- 4-way combine: 3 rounds, g=src writes, g=0 accumulates ----
    float* fb = (float*)&Ht[0][0][0];
    const int cbase = ns * (66 * 64) + lane;
    for (int src = 1; src < 4; ++src) {
        if (g == src) {
#pragma unroll
            for (int s = 0; s < 2; ++s)
#pragma unroll
                for (int c = 0; c < 8; ++c)
#pragma unroll
                    for (int j = 0; j < 4; ++j)
                        fb[cbase + (((s * 8 + c) * 4 + j) << 6)] = acc[s][c][j];
            fb[cbase + (64 << 6)] = S0;
            fb[cbase + (65 << 6)] = S1;
        }
        __syncthreads();
        if (g == 0) {
#pragma unroll
            for (int s = 0; s < 2; ++s)
#pragma unroll
                for (int c = 0; c < 8; ++c)
#pragma unroll
                    for (int j = 0; j < 4; ++j)
                        acc[s][c][j] += fb[cbase + (((s * 8 + c) * 4 + j) << 6)];
            S0 += fb[cbase + (64 << 6)];
            S1 += fb[cbase + (65 << 6)];
        }
        __syncthreads();
    }

    // ---- epilogue (g==0 waves): finish row sums, divide, ELU, store ----
    if (g == 0) {
        S0 += __shfl_xor(S0, 16); S0 += __shfl_xor(S0, 32);
        S1 += __shfl_xor(S1, 16); S1 += __shfl_xor(S1, 32);
        // lane (fr,kg) now holds rowsum(fr); C/D rows are kg*4+j -> permute
#pragma unroll
        for (int s = 0; s < 2; ++s) {
#pragma unroll
            for (int j = 0; j < 4; ++j) {
                float Srow = __shfl(s == 0 ? S0 : S1, kg * 4 + j);
                float inv = 1.0f / Srow;
                int n_out = n0 + ns * 32 + s * 16 + kg * 4 + j;
                float* orow = out + (size_t)n_out * DM + k * FO + fr;
#pragma unroll
                for (int c = 0; c < 8; ++c) {
                    float vv = acc[s][c][j] * inv;
                    float e = vv > 0.f ? vv : (__expf(vv) - 1.0f);
                    orow[c * 16] = e;
                }
            }
        }
    }
}

extern "C" void kernel_launch(void* const* d_in, const int* in_sizes, int n_in,
                              void* d_out, int out_size, void* d_ws, size_t ws_size,
                              hipStream_t stream) {
    const float* x = (const float*)d_in[0];
    const int* mask = (const int*)d_in[1];
    const float* W = (const float*)d_in[2];
    const float* bias = (const float*)d_in[3];
    const float* aL = (const float*)d_in[4];
    const float* aR = (const float*)d_in[5];
    float* out = (float*)d_out;

    char* ws = (char*)d_ws;
    u16* Xh = (u16*)ws;   ws += (size_t)N_NODES * FIN * 2;   // 4.19 MB
    u16* Xl = (u16*)ws;   ws += (size_t)N_NODES * FIN * 2;   // 4.19 MB
    u16* Wh = (u16*)ws;   ws += (size_t)DM * FIN * 2;        // 1.05 MB
    u16* Wl = (u16*)ws;   ws += (size_t)DM * FIN * 2;        // 1.05 MB
    u16* HbT = (u16*)ws;  ws += (size_t)KH * FO * N_NODES * 2; // 8.39 MB
    float2* C2 = (float2*)ws;  ws += (size_t)KH * N_NODES * 8;  // 256 KB
    float2* D2 = (float2*)ws;  ws += (size_t)KH * N_NODES * 8;  // 256 KB
    unsigned long long* mb = (unsigned long long*)ws;        // 2 MB

    split_bf16<<<dim3(2048), dim3(256), 0, stream>>>(x, Xh, Xl, N_NODES * FIN / 4);
    split_bf16<<<dim3(512), dim3(256), 0, stream>>>(W, Wh, Wl, DM * FIN / 4);
    gemm_mfma<<<dim3(8, 32), dim3(512), 0, stream>>>(Xh, Xl, Wh, Wl, bias, aL, aR,
                                                     C2, D2, HbT);
    pack_mask<<<dim3(65536), dim3(256), 0, stream>>>(mask, mb);
    gat_attn<<<dim3(512), dim3(512), 0, stream>>>(HbT, C2, D2, (const unsigned*)mb, out);
}

// Round 11
// 127.008 us; speedup vs baseline: 1.0987x; 1.0987x over previous
//
#include <hip/hip_runtime.h>
#include <hip/hip_bf16.h>

typedef unsigned short u16;
typedef __attribute__((ext_vector_type(8))) short short8;
typedef __attribute__((ext_vector_type(2))) float f32x2;
typedef __attribute__((ext_vector_type(4))) float f32x4;
typedef __attribute__((ext_vector_type(16))) float f32x16;

#define N_NODES 4096
#define FIN 512
#define KH 8
#define FO 128
#define DM 1024   // KH*FO
#define LOG2E 1.44269504088896340736f

__device__ __forceinline__ void gload16(const u16* g, u16* l) {
    __builtin_amdgcn_global_load_lds(
        (const __attribute__((address_space(1))) unsigned int*)g,
        (__attribute__((address_space(3))) unsigned int*)l,
        16, 0, 0);
}

__device__ __forceinline__ unsigned pk_bf16(float lo, float hi) {
    unsigned r;
    asm("v_cvt_pk_bf16_f32 %0, %1, %2" : "=v"(r) : "v"(lo), "v"(hi));
    return r;
}

// ---------------- Kernel P: split fp32 -> (hi, lo) bf16 ----------------
__global__ __launch_bounds__(256) void split_bf16(const float* __restrict__ src,
                                                  u16* __restrict__ hi,
                                                  u16* __restrict__ lo,
                                                  int n4) {
    int idx = blockIdx.x * 256 + threadIdx.x;
    if (idx >= n4) return;
    float4 v = ((const float4*)src)[idx];
    unsigned h01 = pk_bf16(v.x, v.y);
    unsigned h23 = pk_bf16(v.z, v.w);
    float hx = __uint_as_float(h01 << 16);
    float hy = __uint_as_float(h01 & 0xffff0000u);
    float hz = __uint_as_float(h23 << 16);
    float hw = __uint_as_float(h23 & 0xffff0000u);
    unsigned l01 = pk_bf16(v.x - hx, v.y - hy);
    unsigned l23 = pk_bf16(v.z - hz, v.w - hw);
    uint2 hv; hv.x = h01; hv.y = h23;
    uint2 lv; lv.x = l01; lv.y = l23;
    ((uint2*)hi)[idx] = hv;
    ((uint2*)lo)[idx] = lv;
}

// ---------------- Kernel A: MFMA split-bf16 GEMM + bias + C/D factor tables + transpose ----
__global__ __launch_bounds__(512) void gemm_mfma(const u16* __restrict__ Xh,
                                                 const u16* __restrict__ Xl,
                                                 const u16* __restrict__ Wh,
                                                 const u16* __restrict__ Wl,
                                                 const float* __restrict__ bias,
                                                 const float* __restrict__ aL,
                                                 const float* __restrict__ aR,
                                                 float2* __restrict__ C2,
                                                 unsigned* __restrict__ D2b,
                                                 u16* __restrict__ HbT) {
    const int khead = blockIdx.x;
    const int n0 = blockIdx.y * 128;
    const int tid = threadIdx.x;
    const int w = tid >> 6, lane = tid & 63;
    const int wr = w >> 1, wc = w & 1;
    const int c = lane & 31, half = lane >> 5;

    __shared__ u16 S[2][16384];

    const int sa = w >> 1;
    const int shv = w & 1;
    const int scl = lane & 3;
    const int ssw = ((lane >> 2) ^ (lane >> 4)) & 3;
    const int sgc = scl ^ ssw;
    const u16* gb; int growbase;
    if (sa == 0)      { gb = Xh; growbase = n0; }
    else if (sa == 1) { gb = Xl; growbase = n0; }
    else if (sa == 2) { gb = Wh; growbase = khead * 128; }
    else              { gb = Wl; growbase = khead * 128; }
    const u16* glb = gb + (size_t)(growbase + shv * 64 + (lane >> 2)) * FIN + sgc * 8;
    const int sldsoff = sa * 4096 + shv * 64 * 32;

    const int sw = ((c) ^ (c >> 2)) & 3;
    const int aoff = (wr * 32 + c) * 32;
    const int boff0 = 8192 + (wc * 64 + c) * 32;
    const int boff1 = 8192 + (wc * 64 + 32 + c) * 32;

    f32x16 acc0, acc1;
#pragma unroll
    for (int i = 0; i < 16; ++i) { acc0[i] = 0.f; acc1[i] = 0.f; }

#pragma unroll
    for (int i = 0; i < 4; ++i)
        gload16(glb + (size_t)i * 16 * FIN, &S[0][sldsoff + i * 512]);
    __syncthreads();

    int cur = 0;
    for (int kt = 0; kt < 16; ++kt) {
        if (kt < 15) {
            const u16* gsrc = glb + (kt + 1) * 32;
            u16* dst = &S[cur ^ 1][sldsoff];
#pragma unroll
            for (int i = 0; i < 4; ++i)
                gload16(gsrc + (size_t)i * 16 * FIN, dst + i * 512);
        }

        const u16* sp = S[cur];
        short8 ah[2], al8[2], bh[2][2], bl8[2][2];
#pragma unroll
        for (int ks = 0; ks < 2; ++ks) {
            int ch = ((ks * 2 + half) ^ sw) * 8;
            ah[ks]     = *(const short8*)&sp[aoff + ch];
            al8[ks]    = *(const short8*)&sp[4096 + aoff + ch];
            bh[0][ks]  = *(const short8*)&sp[boff0 + ch];
            bl8[0][ks] = *(const short8*)&sp[boff0 + 4096 + ch];
            bh[1][ks]  = *(const short8*)&sp[boff1 + ch];
            bl8[1][ks] = *(const short8*)&sp[boff1 + 4096 + ch];
        }
#pragma unroll
        for (int ks = 0; ks < 2; ++ks) {
            acc0 = __builtin_amdgcn_mfma_f32_32x32x16_bf16(ah[ks], bh[0][ks], acc0, 0, 0, 0);
            acc0 = __builtin_amdgcn_mfma_f32_32x32x16_bf16(ah[ks], bl8[0][ks], acc0, 0, 0, 0);
            acc0 = __builtin_amdgcn_mfma_f32_32x32x16_bf16(al8[ks], bh[0][ks], acc0, 0, 0, 0);
            acc1 = __builtin_amdgcn_mfma_f32_32x32x16_bf16(ah[ks], bh[1][ks], acc1, 0, 0, 0);
            acc1 = __builtin_amdgcn_mfma_f32_32x32x16_bf16(ah[ks], bl8[1][ks], acc1, 0, 0, 0);
            acc1 = __builtin_amdgcn_mfma_f32_32x32x16_bf16(al8[ks], bh[1][ks], acc1, 0, 0, 0);
        }
        __syncthreads();
        cur ^= 1;
    }

    const int fglob = khead * FO + wc * 64 + c;
    float b0 = bias[fglob], b1 = bias[fglob + 32];
#pragma unroll
    for (int r = 0; r < 16; ++r) { acc0[r] += b0; acc1[r] += b1; }

    float alv0 = aL[fglob], alv1 = aL[fglob + 32];
    float arv0 = aR[fglob], arv1 = aR[fglob + 32];
    float pl[16], pr[16];
#pragma unroll
    for (int r = 0; r < 16; ++r) {
        pl[r] = acc0[r] * alv0 + acc1[r] * alv1;
        pr[r] = acc0[r] * arv0 + acc1[r] * arv1;
    }
#pragma unroll
    for (int off = 1; off < 32; off <<= 1) {
#pragma unroll
        for (int r = 0; r < 16; ++r) {
            pl[r] += __shfl_xor(pl[r], off);
            pr[r] += __shfl_xor(pr[r], off);
        }
    }

    u16* T = &S[0][0];
    float* LRf = (float*)&S[0][0] + 9216;

    if (c == 0) {
#pragma unroll
        for (int r = 0; r < 16; ++r) {
            int node = wr * 32 + (r & 3) + 8 * (r >> 2) + 4 * half;
            LRf[(wc * 2 + 0) * 128 + node] = pl[r];
            LRf[(wc * 2 + 1) * 128 + node] = pr[r];
        }
    }

#pragma unroll
    for (int q = 0; q < 4; ++q) {
        int nb = wr * 32 + q * 8 + 4 * half;
        unsigned p00 = pk_bf16(acc0[q * 4 + 0], acc0[q * 4 + 1]);
        unsigned p01 = pk_bf16(acc0[q * 4 + 2], acc0[q * 4 + 3]);
        unsigned p10 = pk_bf16(acc1[q * 4 + 0], acc1[q * 4 + 1]);
        unsigned p11 = pk_bf16(acc1[q * 4 + 2], acc1[q * 4 + 3]);
        *(unsigned*)&T[(wc * 64 + c) * 136 + nb]      = p00;
        *(unsigned*)&T[(wc * 64 + c) * 136 + nb + 2]  = p01;
        *(unsigned*)&T[(wc * 64 + 32 + c) * 136 + nb]     = p10;
        *(unsigned*)&T[(wc * 64 + 32 + c) * 136 + nb + 2] = p11;
    }
    __syncthreads();

    // factor tables: C2 = (exp2(L2E*l), exp2(0.2*L2E*l)) fp32; D2b = packed bf16 pair
    if (wc == 0) {
        int node = wr * 32 + (lane & 31);
        if (lane < 32) {
            float L = (LRf[0 * 128 + node] + LRf[2 * 128 + node]) * LOG2E;
            float2 cv; cv.x = exp2f(L); cv.y = exp2f(0.2f * L);
            C2[(size_t)khead * N_NODES + n0 + node] = cv;
        } else {
            float R = (LRf[1 * 128 + node] + LRf[3 * 128 + node]) * LOG2E;
            D2b[(size_t)khead * N_NODES + n0 + node] = pk_bf16(exp2f(R), exp2f(0.2f * R));
        }
    }

    {
        int f = tid >> 2, q = tid & 3;
        const uint4* src = (const uint4*)&T[f * 136 + q * 32];
        uint4* dst = (uint4*)(HbT + (size_t)(khead * FO + f) * N_NODES + n0 + q * 32);
#pragma unroll
        for (int u = 0; u < 4; ++u) dst[u] = src[u];
    }
}

// ---------------- Kernel D: pack mask (int32 0/1) into bitmask ----------------
__global__ __launch_bounds__(256) void pack_mask(const int* __restrict__ mask,
                                                 unsigned long long* __restrict__ mb) {
    int gid = blockIdx.x * 256 + threadIdx.x;
    int wid = gid >> 6, lane = gid & 63;
    int v = mask[(size_t)wid * 64 + lane];
    unsigned long long bits = __ballot(v != 0);
    if (lane == 0) mb[wid] = bits;
}

// ---------------- Kernel C: flash-style masked softmax + PV aggregation ----------------
// R8-proven structure: flat grid 512, head = blk&7 (head<->XCD pin, L2-resident).
// ONE barrier per m-tile; stage(t+1) + D(t+1) issued at iteration START; free-scheduled
// compute; tail = lgkm0 + counted vmcnt(5) (retires stage, leaves D in flight) + barrier.
// R11 delta: T5 s_setprio(1)/(0) around the MFMA cluster (pure hint, bit-identical).
__global__ __launch_bounds__(512, 4) void gat_attn(const u16* __restrict__ HbT,
                                                   const float2* __restrict__ C2,
                                                   const unsigned* __restrict__ D2b,
                                                   const unsigned long long* __restrict__ mb,
                                                   float* __restrict__ out) {
    const int blk = blockIdx.x;
    const int k = blk & 7;
    const int n0 = (blk >> 3) * 64;
    const int tid = threadIdx.x;
    const int w = tid >> 6, lane = tid & 63;
    const int g = w >> 2, wg = w & 3;
    const int fr = lane & 15, kg = lane >> 4;

    __shared__ u16 Ht[2][2][128 * 64];   // [m-group][buf][tile] = 64 KB

    const int n_a = n0 + wg * 16 + fr;
    const float2 ccf = C2[(size_t)k * N_NODES + n_a];
    const float ccx = ccf.x, ccy = ccf.y;
    const unsigned long long* mrow = mb + (size_t)n_a * 64 + g * 32;
    const int shA = kg * 8, shB = shA + 32;

    f32x4 acc[9];
#pragma unroll
    for (int c = 0; c < 9; ++c) acc[c] = 0.f;

    const short o1 = (fr == 0) ? (short)0x3F80 : (short)0;
    const short8 ones = {o1, o1, o1, o1, o1, o1, o1, o1};

    const int fsub = lane >> 3;
    const int seg = ((lane & 7) ^ fsub) * 8;
    const u16* gstage = HbT + (size_t)(k * FO + wg * 32 + fsub) * N_NODES + g * 2048 + seg;
    u16* lb0 = &Ht[g][0][wg * 2048];
    u16* lb1 = &Ht[g][1][wg * 2048];

    const int frx = fr & 7;
    const int off0 = fr * 64 + (kg ^ frx) * 8;
    const int off1 = fr * 64 + ((kg + 4) ^ frx) * 8;

    const unsigned* D2k = D2b + (size_t)k * N_NODES + g * 2048 + kg * 8;

    // ---- prologue: stage(0)->lb0 [4], D(0) [5]; vmcnt(5) retires stage(0); barrier ----
    uint4 dc0, dc1, dc2, dc3;
    unsigned long long bc;
#pragma unroll
    for (int j = 0; j < 4; ++j)
        gload16(gstage + (size_t)j * 8 * N_NODES, lb0 + j * 512);
    dc0 = *(const uint4*)(D2k);      dc1 = *(const uint4*)(D2k + 4);
    dc2 = *(const uint4*)(D2k + 32); dc3 = *(const uint4*)(D2k + 36);
    bc = mrow[0];
    asm volatile("s_waitcnt vmcnt(5)" ::: "memory");
    __builtin_amdgcn_s_barrier();

// One half-iteration: reads RBUF (tile MT, factors DC*/BITS), stages tile MT+1 into
// SBUF, loads D(MT+1) into DN*/NBITS. Free-scheduled compute; counted-vmcnt tail.
#define ATTN_HALF(RBUF, SBUF, MT, DC0,DC1,DC2,DC3,BITS, DN0,DN1,DN2,DN3,NBITS) do {    \
    const unsigned nxt = ((MT) + 1) & 31;                                               \
    if ((MT) < 31) {                                                                    \
        const u16* gs = gstage + ((size_t)nxt << 6);                                    \
        _Pragma("unroll")                                                               \
        for (int j = 0; j < 4; ++j)                                                     \
            gload16(gs + (size_t)j * 8 * N_NODES, (SBUF) + j * 512);                    \
    }                                                                                   \
    { const unsigned* dnp = D2k + (nxt << 6);                                           \
      DN0 = *(const uint4*)(dnp);      DN1 = *(const uint4*)(dnp + 4);                  \
      DN2 = *(const uint4*)(dnp + 32); DN3 = *(const uint4*)(dnp + 36);                 \
      NBITS = mrow[nxt]; }                                                              \
    __builtin_amdgcn_sched_barrier(0);                                                  \
    {                                                                                   \
        unsigned m32a = (unsigned)((BITS) >> shA);                                      \
        unsigned m32b = (unsigned)((BITS) >> shB);                                      \
        unsigned wa[8] = {DC0.x, DC0.y, DC0.z, DC0.w, DC1.x, DC1.y, DC1.z, DC1.w};      \
        unsigned wb[8] = {DC2.x, DC2.y, DC2.z, DC2.w, DC3.x, DC3.y, DC3.z, DC3.w};      \
        float p0[8], p1[8];                                                             \
        _Pragma("unroll")                                                               \
        for (int v = 0; v < 8; ++v) {                                                   \
            float pa = fmaxf(ccx * __uint_as_float(wa[v] << 16),                        \
                             ccy * __uint_as_float(wa[v] & 0xffff0000u));               \
            unsigned sa2 = (unsigned)(((int)(m32a << (31 - v))) >> 31);                 \
            p0[v] = __uint_as_float(__float_as_uint(pa) & sa2);                         \
            float pb = fmaxf(ccx * __uint_as_float(wb[v] << 16),                        \
                             ccy * __uint_as_float(wb[v] & 0xffff0000u));               \
            unsigned sb2 = (unsigned)(((int)(m32b << (31 - v))) >> 31);                 \
            p1[v] = __uint_as_float(__float_as_uint(pb) & sb2);                         \
        }                                                                               \
        union { unsigned u[4]; short8 s; } ua, ub;                                      \
        _Pragma("unroll")                                                               \
        for (int vp = 0; vp < 4; ++vp) {                                                \
            ua.u[vp] = pk_bf16(p0[2 * vp], p0[2 * vp + 1]);                             \
            ub.u[vp] = pk_bf16(p1[2 * vp], p1[2 * vp + 1]);                             \
        }                                                                               \
        short8 a0 = ua.s, a1 = ub.s;                                                    \
        const u16* hb = (RBUF);                                                         \
        __builtin_amdgcn_s_setprio(1);                                                  \
        _Pragma("unroll")                                                               \
        for (int c = 0; c < 8; ++c) {                                                   \
            short8 b0 = *(const short8*)(hb + c * 1024 + off0);                         \
            short8 b1 = *(const short8*)(hb + c * 1024 + off1);                         \
            acc[c] = __builtin_amdgcn_mfma_f32_16x16x32_bf16(a0, b0, acc[c], 0, 0, 0);  \
            acc[c] = __builtin_amdgcn_mfma_f32_16x16x32_bf16(a1, b1, acc[c], 0, 0, 0);  \
        }                                                                               \
        acc[8] = __builtin_amdgcn_mfma_f32_16x16x32_bf16(a0, ones, acc[8], 0, 0, 0);    \
        acc[8] = __builtin_amdgcn_mfma_f32_16x16x32_bf16(a1, ones, acc[8], 0, 0, 0);    \
        __builtin_amdgcn_s_setprio(0);                                                  \
    }                                                                                   \
    asm volatile("s_waitcnt lgkmcnt(0)" ::: "memory");                                  \
    asm volatile("s_waitcnt vmcnt(5)" ::: "memory");                                    \
    __builtin_amdgcn_s_barrier();                                                       \
} while (0)

    {
        uint4 en0, en1, en2, en3;
        unsigned long long bn;
        // Group base LDS pointers for reads (wave reads the whole group tile)
        const u16* rb0 = &Ht[g][0][0];
        const u16* rb1 = &Ht[g][1][0];
        for (int mt = 0; mt < 32; mt += 2) {
            ATTN_HALF(rb0, lb1, mt,     dc0, dc1, dc2, dc3, bc, en0, en1, en2, en3, bn);
            ATTN_HALF(rb1, lb0, mt + 1, en0, en1, en2, en3, bn, dc0, dc1, dc2, dc3, bc);
        }
    }
#undef ATTN_HALF

    asm volatile("s_waitcnt vmcnt(0)" ::: "memory");
    __syncthreads();   // full drain before LDS reuse

    float* cmb = (float*)&Ht[0][0][0];
    if (g == 1) {
        float* base = cmb + wg * (36 * 64);
#pragma unroll
        for (int c = 0; c < 9; ++c)
#pragma unroll
            for (int j = 0; j < 4; ++j) base[(c * 4 + j) * 64 + lane] = acc[c][j];
    }
    __syncthreads();
    if (g == 0) {
        const float* base = cmb + wg * (36 * 64);
#pragma unroll
        for (int c = 0; c < 9; ++c)
#pragma unroll
            for (int j = 0; j < 4; ++j) acc[c][j] += base[(c * 4 + j) * 64 + lane];

#pragma unroll
        for (int j = 0; j < 4; ++j) {
            float S = __shfl(acc[8][j], (lane & 48));
            float inv = 1.0f / S;
            int n_out = n0 + wg * 16 + kg * 4 + j;
            float* orow = out + (size_t)n_out * DM + k * FO + fr;
#pragma unroll
            for (int c = 0; c < 8; ++c) {
                float v = acc[c][j] * inv;
                float e = v > 0.f ? v : (__expf(v) - 1.0f);
                orow[c * 16] = e;
            }
        }
    }
}

extern "C" void kernel_launch(void* const* d_in, const int* in_sizes, int n_in,
                              void* d_out, int out_size, void* d_ws, size_t ws_size,
                              hipStream_t stream) {
    const float* x = (const float*)d_in[0];
    const int* mask = (const int*)d_in[1];
    const float* W = (const float*)d_in[2];
    const float* bias = (const float*)d_in[3];
    const float* aL = (const float*)d_in[4];
    const float* aR = (const float*)d_in[5];
    float* out = (float*)d_out;

    char* ws = (char*)d_ws;
    u16* Xh = (u16*)ws;   ws += (size_t)N_NODES * FIN * 2;   // 4.19 MB
    u16* Xl = (u16*)ws;   ws += (size_t)N_NODES * FIN * 2;   // 4.19 MB
    u16* Wh = (u16*)ws;   ws += (size_t)DM * FIN * 2;        // 1.05 MB
    u16* Wl = (u16*)ws;   ws += (size_t)DM * FIN * 2;        // 1.05 MB
    u16* HbT = (u16*)ws;  ws += (size_t)KH * FO * N_NODES * 2; // 8.39 MB
    float2* C2 = (float2*)ws;  ws += (size_t)KH * N_NODES * 8;  // 256 KB
    unsigned* D2b = (unsigned*)ws; ws += (size_t)KH * N_NODES * 4; // 128 KB
    unsigned long long* mb = (unsigned long long*)ws;        // 2 MB

    split_bf16<<<dim3(2048), dim3(256), 0, stream>>>(x, Xh, Xl, N_NODES * FIN / 4);
    split_bf16<<<dim3(512), dim3(256), 0, stream>>>(W, Wh, Wl, DM * FIN / 4);
    gemm_mfma<<<dim3(8, 32), dim3(512), 0, stream>>>(Xh, Xl, Wh, Wl, bias, aL, aR,
                                                     C2, D2b, HbT);
    pack_mask<<<dim3(65536), dim3(256), 0, stream>>>(mask, mb);
    gat_attn<<<dim3(512), dim3(512), 0, stream>>>(HbT, C2, D2b, mb, out);
}

// Round 12
// 125.706 us; speedup vs baseline: 1.1101x; 1.0104x over previous
//
#include <hip/hip_runtime.h>
#include <hip/hip_bf16.h>

typedef unsigned short u16;
typedef __attribute__((ext_vector_type(8))) short short8;
typedef __attribute__((ext_vector_type(2))) float f32x2;
typedef __attribute__((ext_vector_type(4))) float f32x4;
typedef __attribute__((ext_vector_type(16))) float f32x16;

#define N_NODES 4096
#define FIN 512
#define KH 8
#define FO 128
#define DM 1024   // KH*FO
#define LOG2E 1.44269504088896340736f

__device__ __forceinline__ void gload16(const u16* g, u16* l) {
    __builtin_amdgcn_global_load_lds(
        (const __attribute__((address_space(1))) unsigned int*)g,
        (__attribute__((address_space(3))) unsigned int*)l,
        16, 0, 0);
}

__device__ __forceinline__ unsigned pk_bf16(float lo, float hi) {
    unsigned r;
    asm("v_cvt_pk_bf16_f32 %0, %1, %2" : "=v"(r) : "v"(lo), "v"(hi));
    return r;
}

// ---------------- Kernel P: split fp32 -> (hi, lo) bf16 ----------------
__global__ __launch_bounds__(256) void split_bf16(const float* __restrict__ src,
                                                  u16* __restrict__ hi,
                                                  u16* __restrict__ lo,
                                                  int n4) {
    int idx = blockIdx.x * 256 + threadIdx.x;
    if (idx >= n4) return;
    float4 v = ((const float4*)src)[idx];
    unsigned h01 = pk_bf16(v.x, v.y);
    unsigned h23 = pk_bf16(v.z, v.w);
    float hx = __uint_as_float(h01 << 16);
    float hy = __uint_as_float(h01 & 0xffff0000u);
    float hz = __uint_as_float(h23 << 16);
    float hw = __uint_as_float(h23 & 0xffff0000u);
    unsigned l01 = pk_bf16(v.x - hx, v.y - hy);
    unsigned l23 = pk_bf16(v.z - hz, v.w - hw);
    uint2 hv; hv.x = h01; hv.y = h23;
    uint2 lv; lv.x = l01; lv.y = l23;
    ((uint2*)hi)[idx] = hv;
    ((uint2*)lo)[idx] = lv;
}

// ---------------- Kernel A: MFMA split-bf16 GEMM + bias + C/D factor tables + transpose ----
__global__ __launch_bounds__(512) void gemm_mfma(const u16* __restrict__ Xh,
                                                 const u16* __restrict__ Xl,
                                                 const u16* __restrict__ Wh,
                                                 const u16* __restrict__ Wl,
                                                 const float* __restrict__ bias,
                                                 const float* __restrict__ aL,
                                                 const float* __restrict__ aR,
                                                 float2* __restrict__ C2,
                                                 unsigned* __restrict__ D2b,
                                                 u16* __restrict__ HbT) {
    const int khead = blockIdx.x;
    const int n0 = blockIdx.y * 128;
    const int tid = threadIdx.x;
    const int w = tid >> 6, lane = tid & 63;
    const int wr = w >> 1, wc = w & 1;
    const int c = lane & 31, half = lane >> 5;

    __shared__ u16 S[2][16384];

    const int sa = w >> 1;
    const int shv = w & 1;
    const int scl = lane & 3;
    const int ssw = ((lane >> 2) ^ (lane >> 4)) & 3;
    const int sgc = scl ^ ssw;
    const u16* gb; int growbase;
    if (sa == 0)      { gb = Xh; growbase = n0; }
    else if (sa == 1) { gb = Xl; growbase = n0; }
    else if (sa == 2) { gb = Wh; growbase = khead * 128; }
    else              { gb = Wl; growbase = khead * 128; }
    const u16* glb = gb + (size_t)(growbase + shv * 64 + (lane >> 2)) * FIN + sgc * 8;
    const int sldsoff = sa * 4096 + shv * 64 * 32;

    const int sw = ((c) ^ (c >> 2)) & 3;
    const int aoff = (wr * 32 + c) * 32;
    const int boff0 = 8192 + (wc * 64 + c) * 32;
    const int boff1 = 8192 + (wc * 64 + 32 + c) * 32;

    f32x16 acc0, acc1;
#pragma unroll
    for (int i = 0; i < 16; ++i) { acc0[i] = 0.f; acc1[i] = 0.f; }

#pragma unroll
    for (int i = 0; i < 4; ++i)
        gload16(glb + (size_t)i * 16 * FIN, &S[0][sldsoff + i * 512]);
    __syncthreads();

    int cur = 0;
    for (int kt = 0; kt < 16; ++kt) {
        if (kt < 15) {
            const u16* gsrc = glb + (kt + 1) * 32;
            u16* dst = &S[cur ^ 1][sldsoff];
#pragma unroll
            for (int i = 0; i < 4; ++i)
                gload16(gsrc + (size_t)i * 16 * FIN, dst + i * 512);
        }

        const u16* sp = S[cur];
        short8 ah[2], al8[2], bh[2][2], bl8[2][2];
#pragma unroll
        for (int ks = 0; ks < 2; ++ks) {
            int ch = ((ks * 2 + half) ^ sw) * 8;
            ah[ks]     = *(const short8*)&sp[aoff + ch];
            al8[ks]    = *(const short8*)&sp[4096 + aoff + ch];
            bh[0][ks]  = *(const short8*)&sp[boff0 + ch];
            bl8[0][ks] = *(const short8*)&sp[boff0 + 4096 + ch];
            bh[1][ks]  = *(const short8*)&sp[boff1 + ch];
            bl8[1][ks] = *(const short8*)&sp[boff1 + 4096 + ch];
        }
#pragma unroll
        for (int ks = 0; ks < 2; ++ks) {
            acc0 = __builtin_amdgcn_mfma_f32_32x32x16_bf16(ah[ks], bh[0][ks], acc0, 0, 0, 0);
            acc0 = __builtin_amdgcn_mfma_f32_32x32x16_bf16(ah[ks], bl8[0][ks], acc0, 0, 0, 0);
            acc0 = __builtin_amdgcn_mfma_f32_32x32x16_bf16(al8[ks], bh[0][ks], acc0, 0, 0, 0);
            acc1 = __builtin_amdgcn_mfma_f32_32x32x16_bf16(ah[ks], bh[1][ks], acc1, 0, 0, 0);
            acc1 = __builtin_amdgcn_mfma_f32_32x32x16_bf16(ah[ks], bl8[1][ks], acc1, 0, 0, 0);
            acc1 = __builtin_amdgcn_mfma_f32_32x32x16_bf16(al8[ks], bh[1][ks], acc1, 0, 0, 0);
        }
        __syncthreads();
        cur ^= 1;
    }

    const int fglob = khead * FO + wc * 64 + c;
    float b0 = bias[fglob], b1 = bias[fglob + 32];
#pragma unroll
    for (int r = 0; r < 16; ++r) { acc0[r] += b0; acc1[r] += b1; }

    float alv0 = aL[fglob], alv1 = aL[fglob + 32];
    float arv0 = aR[fglob], arv1 = aR[fglob + 32];
    float pl[16], pr[16];
#pragma unroll
    for (int r = 0; r < 16; ++r) {
        pl[r] = acc0[r] * alv0 + acc1[r] * alv1;
        pr[r] = acc0[r] * arv0 + acc1[r] * arv1;
    }
#pragma unroll
    for (int off = 1; off < 32; off <<= 1) {
#pragma unroll
        for (int r = 0; r < 16; ++r) {
            pl[r] += __shfl_xor(pl[r], off);
            pr[r] += __shfl_xor(pr[r], off);
        }
    }

    u16* T = &S[0][0];
    float* LRf = (float*)&S[0][0] + 9216;

    if (c == 0) {
#pragma unroll
        for (int r = 0; r < 16; ++r) {
            int node = wr * 32 + (r & 3) + 8 * (r >> 2) + 4 * half;
            LRf[(wc * 2 + 0) * 128 + node] = pl[r];
            LRf[(wc * 2 + 1) * 128 + node] = pr[r];
        }
    }

#pragma unroll
    for (int q = 0; q < 4; ++q) {
        int nb = wr * 32 + q * 8 + 4 * half;
        unsigned p00 = pk_bf16(acc0[q * 4 + 0], acc0[q * 4 + 1]);
        unsigned p01 = pk_bf16(acc0[q * 4 + 2], acc0[q * 4 + 3]);
        unsigned p10 = pk_bf16(acc1[q * 4 + 0], acc1[q * 4 + 1]);
        unsigned p11 = pk_bf16(acc1[q * 4 + 2], acc1[q * 4 + 3]);
        *(unsigned*)&T[(wc * 64 + c) * 136 + nb]      = p00;
        *(unsigned*)&T[(wc * 64 + c) * 136 + nb + 2]  = p01;
        *(unsigned*)&T[(wc * 64 + 32 + c) * 136 + nb]     = p10;
        *(unsigned*)&T[(wc * 64 + 32 + c) * 136 + nb + 2] = p11;
    }
    __syncthreads();

    // factor tables: C2 = (exp2(L2E*l), exp2(0.2*L2E*l)) fp32; D2b = packed bf16 pair
    if (wc == 0) {
        int node = wr * 32 + (lane & 31);
        if (lane < 32) {
            float L = (LRf[0 * 128 + node] + LRf[2 * 128 + node]) * LOG2E;
            float2 cv; cv.x = exp2f(L); cv.y = exp2f(0.2f * L);
            C2[(size_t)khead * N_NODES + n0 + node] = cv;
        } else {
            float R = (LRf[1 * 128 + node] + LRf[3 * 128 + node]) * LOG2E;
            D2b[(size_t)khead * N_NODES + n0 + node] = pk_bf16(exp2f(R), exp2f(0.2f * R));
        }
    }

    {
        int f = tid >> 2, q = tid & 3;
        const uint4* src = (const uint4*)&T[f * 136 + q * 32];
        uint4* dst = (uint4*)(HbT + (size_t)(khead * FO + f) * N_NODES + n0 + q * 32);
#pragma unroll
        for (int u = 0; u < 4; ++u) dst[u] = src[u];
    }
}

// ---------------- Kernel D: pack mask (int32 0/1) into bitmask ----------------
__global__ __launch_bounds__(256) void pack_mask(const int* __restrict__ mask,
                                                 unsigned long long* __restrict__ mb) {
    int gid = blockIdx.x * 256 + threadIdx.x;
    int wid = gid >> 6, lane = gid & 63;
    int v = mask[(size_t)wid * 64 + lane];
    unsigned long long bits = __ballot(v != 0);
    if (lane == 0) mb[wid] = bits;
}

// ---------------- Kernel C: flash-style masked softmax + PV aggregation ----------------
// R11-anchor schedule, NEW geometry: 8 waves = ns(2 x 32-row) x g(2 x 2048-m) x
// ks(2 x 32-m slice of the 64-m tile). Each wave: 2 A-frags (rows fr, fr+16),
// 8 ds_read_b128/iter (each feeds 2 MFMAs -> B redundancy 4x->2x), 18 MFMAs.
// Per iter: [D(t)+masks 4 loads FIFO-first] [stage(t+1) 4] -> P-gen (auto vmcnt(4),
// stage in flight through compute) -> MFMA -> lgkm0 + vmcnt(0) (stage aged) + barrier.
__global__ __launch_bounds__(512, 4) void gat_attn(const u16* __restrict__ HbT,
                                                   const float2* __restrict__ C2,
                                                   const unsigned* __restrict__ D2b,
                                                   const unsigned* __restrict__ mb32,
                                                   float* __restrict__ out) {
    const int blk = blockIdx.x;
    const int k = blk & 7;
    const int n0 = (blk >> 3) * 64;
    const int tid = threadIdx.x;
    const int w = tid >> 6, lane = tid & 63;
    const int ns = w & 1, g = (w >> 1) & 1, ks = w >> 2;
    const int fr = lane & 15, kg = lane >> 4;

    __shared__ u16 Ht[2][2][128 * 64];   // [m-group][buf][128f x 64m] = 64 KB

    const int na0 = n0 + ns * 32 + fr;
    const int na1 = na0 + 16;
    const float2 c0f = C2[(size_t)k * N_NODES + na0];
    const float2 c1f = C2[(size_t)k * N_NODES + na1];
    const float cx0 = c0f.x, cy0 = c0f.y;
    const float cx1 = c1f.x, cy1 = c1f.y;
    // u32 mask word (mt): bits for m = g*2048 + mt*64 + ks*32 .. +31
    const unsigned* mp0 = mb32 + (size_t)na0 * 128 + g * 64 + ks;
    const unsigned* mp1 = mb32 + (size_t)na1 * 128 + g * 64 + ks;

    f32x4 acc[2][9];
#pragma unroll
    for (int s = 0; s < 2; ++s)
#pragma unroll
        for (int c = 0; c < 9; ++c) acc[s][c] = 0.f;

    const short o1 = (fr == 0) ? (short)0x3F80 : (short)0;
    const short8 ones = {o1, o1, o1, o1, o1, o1, o1, o1};

    // staging quadrant q = ns*2+ks stages f-rows q*32..+31 of group g's tile
    const int q = ns * 2 + ks;
    const int fsub = lane >> 3;
    const int seg = ((lane & 7) ^ fsub) * 8;
    const u16* gstage = HbT + (size_t)(k * FO + q * 32 + fsub) * N_NODES + g * 2048 + seg;
    u16* lbA = &Ht[g][0][q * 2048];
    u16* lbB = &Ht[g][1][q * 2048];

    // read: B-frag rows c*16+fr, m-chunk (ks*4+kg) ^ (fr&7)  (R8-proven pattern)
    const int frx = fr & 7;
    const int offb = fr * 64 + ((ks * 4 + kg) ^ frx) * 8;

    const unsigned* D2k = D2b + (size_t)k * N_NODES + g * 2048 + ks * 32 + kg * 8;

    // ---- prologue: stage tile0 -> buf0; own-wait; barrier ----
#pragma unroll
    for (int j = 0; j < 4; ++j)
        gload16(gstage + (size_t)j * 8 * N_NODES, lbA + j * 512);
    asm volatile("s_waitcnt vmcnt(0)" ::: "memory");
    __builtin_amdgcn_s_barrier();

#define ATTN_STEP(RBUF, SBUF, MT) do {                                                  \
    const int mtv = (MT);                                                               \
    /* (1) D(t)+masks FIFO-first: P-wait = vmcnt(4) leaves stage in flight */           \
    const unsigned* dp = D2k + mtv * 64;                                                \
    uint4 d0 = *(const uint4*)(dp);                                                     \
    uint4 d1 = *(const uint4*)(dp + 4);                                                 \
    unsigned m0w = mp0[mtv * 2];                                                        \
    unsigned m1w = mp1[mtv * 2];                                                        \
    /* (2) stage(t+1) */                                                                \
    if (mtv < 31) {                                                                     \
        const u16* gs = gstage + ((size_t)(mtv + 1) << 6);                              \
        _Pragma("unroll")                                                               \
        for (int j = 0; j < 4; ++j)                                                     \
            gload16(gs + (size_t)j * 8 * N_NODES, (SBUF) + j * 512);                    \
    }                                                                                   \
    __builtin_amdgcn_sched_barrier(0);                                                  \
    /* (3) P-gen: 8 m x 2 rowsets, fused pack */                                        \
    {                                                                                   \
        unsigned mq0 = m0w >> (kg * 8);                                                 \
        unsigned mq1 = m1w >> (kg * 8);                                                 \
        unsigned wa[8] = {d0.x, d0.y, d0.z, d0.w, d1.x, d1.y, d1.z, d1.w};              \
        union { unsigned u[4]; short8 s; } ua, ub;                                      \
        _Pragma("unroll")                                                               \
        for (int vp = 0; vp < 4; ++vp) {                                                \
            unsigned u0 = wa[2 * vp], u1 = wa[2 * vp + 1];                              \
            float dx0 = __uint_as_float(u0 << 16);                                      \
            float dy0 = __uint_as_float(u0 & 0xffff0000u);                              \
            float dx1 = __uint_as_float(u1 << 16);                                      \
            float dy1 = __uint_as_float(u1 & 0xffff0000u);                              \
            unsigned s00 = (unsigned)(((int)(mq0 << (31 - 2 * vp))) >> 31);             \
            unsigned s01 = (unsigned)(((int)(mq0 << (30 - 2 * vp))) >> 31);             \
            unsigned s10 = (unsigned)(((int)(mq1 << (31 - 2 * vp))) >> 31);             \
            unsigned s11 = (unsigned)(((int)(mq1 << (30 - 2 * vp))) >> 31);             \
            float q0a = __uint_as_float(__float_as_uint(fmaxf(cx0 * dx0, cy0 * dy0)) & s00); \
            float q0b = __uint_as_float(__float_as_uint(fmaxf(cx0 * dx1, cy0 * dy1)) & s01); \
            float q1a = __uint_as_float(__float_as_uint(fmaxf(cx1 * dx0, cy1 * dy0)) & s10); \
            float q1b = __uint_as_float(__float_as_uint(fmaxf(cx1 * dx1, cy1 * dy1)) & s11); \
            ua.u[vp] = pk_bf16(q0a, q0b);                                               \
            ub.u[vp] = pk_bf16(q1a, q1b);                                               \
        }                                                                               \
        short8 a0 = ua.s, a1 = ub.s;                                                    \
        /* (4) ds_read + MFMA: 8 reads feed 16 row-MFMAs + 2 ones */                    \
        const u16* hb = (RBUF);                                                         \
        __builtin_amdgcn_s_setprio(1);                                                  \
        _Pragma("unroll")                                                               \
        for (int c = 0; c < 8; ++c) {                                                   \
            short8 b = *(const short8*)(hb + c * 1024 + offb);                          \
            acc[0][c] = __builtin_amdgcn_mfma_f32_16x16x32_bf16(a0, b, acc[0][c], 0, 0, 0); \
            acc[1][c] = __builtin_amdgcn_mfma_f32_16x16x32_bf16(a1, b, acc[1][c], 0, 0, 0); \
        }                                                                               \
        acc[0][8] = __builtin_amdgcn_mfma_f32_16x16x32_bf16(a0, ones, acc[0][8], 0, 0, 0);  \
        acc[1][8] = __builtin_amdgcn_mfma_f32_16x16x32_bf16(a1, ones, acc[1][8], 0, 0, 0);  \
        __builtin_amdgcn_s_setprio(0);                                                  \
    }                                                                                   \
    /* (5) own-wait-then-barrier: stage aged through full compute */                    \
    asm volatile("s_waitcnt lgkmcnt(0)" ::: "memory");                                  \
    asm volatile("s_waitcnt vmcnt(0)" ::: "memory");                                    \
    __builtin_amdgcn_s_barrier();                                                       \
} while (0)

    {
        const u16* rb0 = &Ht[g][0][0];
        const u16* rb1 = &Ht[g][1][0];
        for (int mt = 0; mt < 32; mt += 2) {
            ATTN_STEP(rb0, lbB, mt);
            ATTN_STEP(rb1, lbA, mt + 1);
        }
    }
#undef ATTN_STEP

    __syncthreads();   // all drained by last tail; safe to reuse LDS

    // ---- 4-way combine (g,ks): 3 rounds, receiver = (g==0 && ks==0) ----
    float* fb = (float*)&Ht[0][0][0];
    const int myid = g + 2 * ks;
    const int cb = ns * 4608 + lane;
    for (int src = 1; src < 4; ++src) {
        if (myid == src) {
#pragma unroll
            for (int s = 0; s < 2; ++s)
#pragma unroll
                for (int c = 0; c < 9; ++c)
#pragma unroll
                    for (int j = 0; j < 4; ++j)
                        fb[cb + (((s * 9 + c) * 4 + j) << 6)] = acc[s][c][j];
        }
        __syncthreads();
        if (myid == 0) {
#pragma unroll
            for (int s = 0; s < 2; ++s)
#pragma unroll
                for (int c = 0; c < 9; ++c)
#pragma unroll
                    for (int j = 0; j < 4; ++j)
                        acc[s][c][j] += fb[cb + (((s * 9 + c) * 4 + j) << 6)];
        }
        __syncthreads();
    }

    // ---- epilogue (receiver waves): divide by S, ELU, store ----
    if (myid == 0) {
#pragma unroll
        for (int s = 0; s < 2; ++s) {
#pragma unroll
            for (int j = 0; j < 4; ++j) {
                float S = __shfl(acc[s][8][j], (lane & 48));
                float inv = 1.0f / S;
                int n_out = n0 + ns * 32 + s * 16 + kg * 4 + j;
                float* orow = out + (size_t)n_out * DM + k * FO + fr;
#pragma unroll
                for (int c = 0; c < 8; ++c) {
                    float v = acc[s][c][j] * inv;
                    float e = v > 0.f ? v : (__expf(v) - 1.0f);
                    orow[c * 16] = e;
                }
            }
        }
    }
}

extern "C" void kernel_launch(void* const* d_in, const int* in_sizes, int n_in,
                              void* d_out, int out_size, void* d_ws, size_t ws_size,
                              hipStream_t stream) {
    const float* x = (const float*)d_in[0];
    const int* mask = (const int*)d_in[1];
    const float* W = (const float*)d_in[2];
    const float* bias = (const float*)d_in[3];
    const float* aL = (const float*)d_in[4];
    const float* aR = (const float*)d_in[5];
    float* out = (float*)d_out;

    char* ws = (char*)d_ws;
    u16* Xh = (u16*)ws;   ws += (size_t)N_NODES * FIN * 2;   // 4.19 MB
    u16* Xl = (u16*)ws;   ws += (size_t)N_NODES * FIN * 2;   // 4.19 MB
    u16* Wh = (u16*)ws;   ws += (size_t)DM * FIN * 2;        // 1.05 MB
    u16* Wl = (u16*)ws;   ws += (size_t)DM * FIN * 2;        // 1.05 MB
    u16* HbT = (u16*)ws;  ws += (size_t)KH * FO * N_NODES * 2; // 8.39 MB
    float2* C2 = (float2*)ws;  ws += (size_t)KH * N_NODES * 8;  // 256 KB
    unsigned* D2b = (unsigned*)ws; ws += (size_t)KH * N_NODES * 4; // 128 KB
    unsigned long long* mb = (unsigned long long*)ws;        // 2 MB

    split_bf16<<<dim3(2048), dim3(256), 0, stream>>>(x, Xh, Xl, N_NODES * FIN / 4);
    split_bf16<<<dim3(512), dim3(256), 0, stream>>>(W, Wh, Wl, DM * FIN / 4);
    gemm_mfma<<<dim3(8, 32), dim3(512), 0, stream>>>(Xh, Xl, Wh, Wl, bias, aL, aR,
                                                     C2, D2b, HbT);
    pack_mask<<<dim3(65536), dim3(256), 0, stream>>>(mask, mb);
    gat_attn<<<dim3(512), dim3(512), 0, stream>>>(HbT, C2, D2b, (const unsigned*)mb, out);
}